// Round 8
// baseline (287.632 us; speedup 1.0000x reference)
//
#include <hip/hip_runtime.h>
#include <stdint.h>

#define B_ 8
#define S_ 2048
#define D_ 512
#define U_ 512
#define M_TOTAL (B_*S_)   // 16384
#define NPROJ (2*U_)      // 1024
#define QBLK 32
#define KVBLK 64
#define NIT (S_/KVBLK)    // 32
#define LOG2E 1.4426950408889634f

typedef __attribute__((ext_vector_type(8))) _Float16 f16x8;
typedef __attribute__((ext_vector_type(4))) float f32x4;

__device__ __forceinline__ uint16_t f2h(float f){
  return __builtin_bit_cast(uint16_t, (_Float16)f);
}

__device__ __forceinline__ void gload16(const void* g, void* l){
  __builtin_amdgcn_global_load_lds(
      (const __attribute__((address_space(1))) void*)g,
      (__attribute__((address_space(3))) void*)l, 16, 0, 0);
}

// Stage one half-tile [ROWS x 64] f16 into linear LDS, global source pre-swizzled.
template<int ROWS>
__device__ __forceinline__ void stage_half(char* lbase, const uint16_t* __restrict__ gpanel,
                                           int ld, int wv, int lane){
  int r0 = wv*8 + (lane>>3);
  int gs = ((lane&7) ^ (r0&7)) << 3;
  gload16(gpanel + (size_t)r0*ld + gs, lbase + wv*1024);
  if constexpr (ROWS==128){
    gload16(gpanel + (size_t)(r0+64)*ld + gs, lbase + 8192 + wv*1024);
  }
}

// ---- prep: WT[u][d] = f16(W[d][u]); u<512 -> Ww, else Uw ----
__global__ __launch_bounds__(256) void prep_w(const float* __restrict__ Ww,
                                              const float* __restrict__ Uw,
                                              uint16_t* __restrict__ WT){
  int idx = blockIdx.x*256 + threadIdx.x;
  int u = idx >> 9;
  int d = idx & 511;
  float v = (u < U_) ? Ww[d*U_ + u] : Uw[d*U_ + (u-U_)];
  WT[idx] = f2h(v);
}

// ---- prep: Xf[b][s][d] f16 row-major; XT[b][d][s] f16 transposed ----
__global__ __launch_bounds__(256) void prep_x(const float* __restrict__ X,
                                              uint16_t* __restrict__ Xf,
                                              uint16_t* __restrict__ XT){
  __shared__ float tile[32][33];
  int b = blockIdx.z;
  int s0 = blockIdx.x * 32;
  int d0 = blockIdx.y * 32;
  int tid = threadIdx.x;
  int tr = tid >> 5;
  int tc = tid & 31;
  const float* Xb = X + (size_t)b*S_*D_;
#pragma unroll
  for (int i = 0; i < 32; i += 8){
    size_t off = (size_t)(s0+tr+i)*D_ + d0+tc;
    float v = Xb[off];
    tile[tr+i][tc] = v;
    Xf[(size_t)b*S_*D_ + off] = f2h(v);
  }
  __syncthreads();
  uint16_t* XTb = XT + (size_t)b*D_*S_;
#pragma unroll
  for (int i = 0; i < 32; i += 8)
    XTb[(size_t)(d0+tr+i)*S_ + s0+tc] = f2h(tile[tc][tr+i]);
}

// ---- 8-phase NT projection GEMM; Q output pre-scaled by log2(e) ----
__global__ __launch_bounds__(512, 2) void gemm_proj(
    const uint16_t* __restrict__ A, int lda,
    const uint16_t* __restrict__ Bp, int ldb,
    uint16_t* __restrict__ Qo, uint16_t* __restrict__ Ko,
    const float* __restrict__ biasW, const float* __restrict__ biasU,
    int KD)
{
  constexpr int BMH   = 128;
  constexpr int MFR   = 8;
  constexpr int AHALF = BMH*128;
  constexpr int BHALF = 128*128;
  constexpr int DSTR  = 2*AHALF + 2*BHALF;
  __shared__ __align__(16) char smem[2*DSTR];

  const int m0 = blockIdx.y * 256;
  const int n0 = blockIdx.x * 256;
  const uint16_t* Apan = A  + (size_t)m0*lda;
  const uint16_t* Bpan = Bp + (size_t)n0*ldb;

  const int t512 = threadIdx.x;
  const int wv   = t512 >> 6;
  const int lane = t512 & 63;
  const int wm   = wv >> 2;
  const int wn   = wv & 3;
  const int fr   = lane & 15;
  const int fg   = lane >> 4;
  const int sw   = fr & 7;

  const int NT = KD >> 6;

  auto Aslot = [&](int par, int h){ return smem + par*DSTR + h*AHALF; };
  auto Bslot = [&](int par, int h){ return smem + par*DSTR + 2*AHALF + h*BHALF; };

  stage_half<128>(Aslot(0,0), Apan,                   lda, wv, lane);
  stage_half<128>(Aslot(0,1), Apan + (size_t)128*lda, lda, wv, lane);
  stage_half<128>(Bslot(0,0), Bpan,                   ldb, wv, lane);
  stage_half<128>(Bslot(0,1), Bpan + (size_t)128*ldb, ldb, wv, lane);
  if (NT > 1)
    stage_half<128>(Aslot(1,0), Apan + 64,            lda, wv, lane);
  asm volatile("s_waitcnt vmcnt(2)" ::: "memory");
  __builtin_amdgcn_s_barrier();

  f32x4 acc[MFR][4];
#pragma unroll
  for (int i=0;i<MFR;i++)
#pragma unroll
    for (int j=0;j<4;j++) acc[i][j] = (f32x4){0.f,0.f,0.f,0.f};

  for (int t = 0; t < NT; ++t){
    const int p = t & 1;
    const char* myA = Aslot(p, wm);
    const char* myB = Bslot(p, wn>>1);
    f16x8 af[MFR];

    auto rdA = [&](int ks){
#pragma unroll
      for (int mf=0; mf<MFR; ++mf)
        af[mf] = *(const f16x8*)(myA + (mf*16+fr)*128 + (((ks<<2)|fg) ^ sw)*16);
    };
    auto rdB = [&](int ks, int nh, f16x8& b0, f16x8& b1){
      int rb = (wn&1)*64 + nh*32 + fr;
      b0 = *(const f16x8*)(myB + rb*128      + (((ks<<2)|fg) ^ sw)*16);
      b1 = *(const f16x8*)(myB + (rb+16)*128 + (((ks<<2)|fg) ^ sw)*16);
    };
    auto mm = [&](int nh, f16x8 b0, f16x8 b1){
      __builtin_amdgcn_s_setprio(1);
#pragma unroll
      for (int mf=0; mf<MFR; ++mf){
        acc[mf][nh*2]   = __builtin_amdgcn_mfma_f32_16x16x32_f16(af[mf], b0, acc[mf][nh*2],   0,0,0);
        acc[mf][nh*2+1] = __builtin_amdgcn_mfma_f32_16x16x32_f16(af[mf], b1, acc[mf][nh*2+1], 0,0,0);
      }
      __builtin_amdgcn_s_setprio(0);
    };

    f16x8 b0, b1;
    rdA(0); rdB(0, 0, b0, b1);
    if (t+1 < NT)
      stage_half<128>(Aslot(p^1,1), Apan + (size_t)128*lda + (t+1)*64, lda, wv, lane);
    __builtin_amdgcn_s_barrier();
    mm(0, b0, b1);
    __builtin_amdgcn_s_barrier();
    rdB(0, 1, b0, b1);
    if (t+1 < NT)
      stage_half<128>(Bslot(p^1,0), Bpan + (t+1)*64, ldb, wv, lane);
    __builtin_amdgcn_s_barrier();
    mm(1, b0, b1);
    __builtin_amdgcn_s_barrier();
    rdA(1); rdB(1, 0, b0, b1);
    if (t+1 < NT)
      stage_half<128>(Bslot(p^1,1), Bpan + (size_t)128*ldb + (t+1)*64, ldb, wv, lane);
    __builtin_amdgcn_s_barrier();
    mm(0, b0, b1);
    __builtin_amdgcn_s_barrier();
    rdB(1, 1, b0, b1);
    if (t+2 < NT)
      stage_half<128>(Aslot(p,0), Apan + (t+2)*64, lda, wv, lane);
    __builtin_amdgcn_s_barrier();
    mm(1, b0, b1);
    asm volatile("s_waitcnt vmcnt(2)" ::: "memory");
    __builtin_amdgcn_s_barrier();
  }

#pragma unroll
  for (int mf=0; mf<MFR; ++mf)
#pragma unroll
    for (int nf=0; nf<4; ++nf){
      int col  = n0 + wn*64 + nf*16 + fr;
      int rowb = m0 + wm*128 + mf*16 + fg*4;
      f32x4 a = acc[mf][nf];
      float bias = (col < U_) ? biasW[col] : biasU[col - U_];
      if (col < U_){
#pragma unroll
        for (int r=0;r<4;r++) Qo[(size_t)(rowb+r)*U_ + col] = f2h((a[r] + bias)*LOG2E);
      } else {
#pragma unroll
        for (int r=0;r<4;r++) Ko[(size_t)(rowb+r)*U_ + col - U_] = f2h(a[r] + bias);
      }
    }
}

// ---- fused flash attention v4: 4 waves, QBLK=32, 2 blocks/CU ----
// Q staged once in LDS (swizzled); K,V direct global(L2)->reg each iter.
// QK waves (kh=wv&1, ks=wv>>1): 32q x 32kv over K-half; partials in Ss[ks].
// PV waves wd=wv: 32q x 128d. 2 barriers/iter.
__global__ __launch_bounds__(256, 2) void flash_attn(
    const uint16_t* __restrict__ Qf,   // [B*S][512] f16 (pre-scaled by log2e)
    const uint16_t* __restrict__ Kf,   // [B*S][512] f16
    const uint16_t* __restrict__ XT,   // [B][512][2048] f16
    float* __restrict__ Out)           // [B*S][512] f32
{
  __shared__ __align__(16) uint16_t Qs[QBLK][512];     // 32 KB (granule-swizzled)
  __shared__ __align__(16) float    Ss[2][QBLK][68];   // 17.4 KB
  __shared__ __align__(16) uint16_t Ps[QBLK][KVBLK];   // 4 KB (granule-swizzled)
  __shared__ float m_s[QBLK], l_s[QBLK], f_s[QBLK];

  const int bid   = blockIdx.x;
  const int batch = bid & 7;
  const int s0    = (bid >> 3) * QBLK;

  const int t    = threadIdx.x;
  const int wv   = t >> 6;          // 0..3
  const int lane = t & 63;
  const int fr   = lane & 15;
  const int fg   = lane >> 4;
  const int kh   = wv & 1;          // QK kv-half
  const int ks_  = wv >> 1;         // QK K-dim half
  const int wd   = wv;              // PV d-slice of 128
  const int srow = t >> 3;          // softmax row 0..31
  const int sj   = t & 7;           // softmax chunk 0..7

  const uint16_t* Krow = Kf + (size_t)batch*S_*U_;
  const uint16_t* Vt   = XT + (size_t)batch*D_*S_;

  // ---- stage Q into LDS (once): row = i*4+wv, granule = lane, swizzled src ----
  {
    const uint16_t* Qb = Qf + ((size_t)batch*S_ + s0)*U_;
#pragma unroll
    for (int i=0;i<8;++i){
      int row = i*4 + wv;
      gload16(Qb + (size_t)row*U_ + ((lane ^ (row&7))<<3),
              (char*)Qs + i*4096 + wv*1024);
    }
  }
  if (t < QBLK){ m_s[t] = -3e38f; l_s[t] = 0.f; }
  f32x4 acc[2][8];
#pragma unroll
  for (int i=0;i<2;i++)
#pragma unroll
    for (int j=0;j<8;j++) acc[i][j] = (f32x4){0.f,0.f,0.f,0.f};
  asm volatile("s_waitcnt vmcnt(0) lgkmcnt(0)" ::: "memory");
  __builtin_amdgcn_s_barrier();                     // Qs certified
  __builtin_amdgcn_sched_barrier(0);

  for (int it=0; it<NIT; ++it){
    // ---- K(it) direct global->reg: 32kv(kh) x 256k(ks) per wave ----
    f16x8 kreg[2][8];
    {
      const uint16_t* Kb = Krow + (size_t)(it*KVBLK + kh*32)*U_ + ks_*256;
#pragma unroll
      for (int kvf=0; kvf<2; ++kvf)
#pragma unroll
        for (int kk=0; kk<8; ++kk)
          kreg[kvf][kk] = *(const f16x8*)(Kb + (size_t)(kvf*16+fr)*U_ + kk*32 + fg*8);
    }
    // ---- QK^T: A-frags from Qs, 4 indep chains ----
    f32x4 sfr[2][2];
#pragma unroll
    for (int a=0;a<2;a++)
#pragma unroll
      for (int b=0;b<2;b++) sfr[a][b] = (f32x4){0.f,0.f,0.f,0.f};
    __builtin_amdgcn_s_setprio(1);
#pragma unroll
    for (int kk=0; kk<8; ++kk){
      int g = (ks_<<5) | (kk<<2) | fg;
      f16x8 aq0 = *(const f16x8*)((const char*)Qs + (fr)*1024      + ((g ^ (fr&7))<<4));
      f16x8 aq1 = *(const f16x8*)((const char*)Qs + (16+fr)*1024   + ((g ^ (fr&7))<<4));
      sfr[0][0] = __builtin_amdgcn_mfma_f32_16x16x32_f16(aq0, kreg[0][kk], sfr[0][0], 0,0,0);
      sfr[0][1] = __builtin_amdgcn_mfma_f32_16x16x32_f16(aq0, kreg[1][kk], sfr[0][1], 0,0,0);
      sfr[1][0] = __builtin_amdgcn_mfma_f32_16x16x32_f16(aq1, kreg[0][kk], sfr[1][0], 0,0,0);
      sfr[1][1] = __builtin_amdgcn_mfma_f32_16x16x32_f16(aq1, kreg[1][kk], sfr[1][1], 0,0,0);
    }
    __builtin_amdgcn_s_setprio(0);
#pragma unroll
    for (int qt=0; qt<2; ++qt)
#pragma unroll
      for (int kvf=0; kvf<2; ++kvf)
#pragma unroll
        for (int r=0; r<4; ++r)
          Ss[ks_][qt*16 + fg*4 + r][kh*32 + kvf*16 + fr] = sfr[qt][kvf][r];
    asm volatile("s_waitcnt lgkmcnt(0)" ::: "memory");
    __builtin_amdgcn_s_barrier();                   // B1: S partials published
    __builtin_amdgcn_sched_barrier(0);

    // ---- V(it) issue early (used in PV) ----
    f16x8 vreg[2][8];
#pragma unroll
    for (int vk=0; vk<2; ++vk)
#pragma unroll
      for (int dt=0; dt<8; ++dt)
        vreg[vk][dt] = *(const f16x8*)(Vt + (size_t)(wd*128 + dt*16 + fr)*S_
                                       + it*KVBLK + vk*32 + fg*8);
    __builtin_amdgcn_sched_barrier(0);              // pin issue before softmax

    // ---- online softmax (log2 domain): row = t>>3, chunk = t&7 ----
    {
      float4 a0 = *(const float4*)&Ss[0][srow][sj*8];
      float4 a1 = *(const float4*)&Ss[0][srow][sj*8+4];
      float4 c0 = *(const float4*)&Ss[1][srow][sj*8];
      float4 c1 = *(const float4*)&Ss[1][srow][sj*8+4];
      float v0 = a0.x+c0.x, v1 = a0.y+c0.y, v2 = a0.z+c0.z, v3 = a0.w+c0.w;
      float v4 = a1.x+c1.x, v5 = a1.y+c1.y, v6 = a1.z+c1.z, v7 = a1.w+c1.w;
      float pm = fmaxf(fmaxf(fmaxf(v0,v1),fmaxf(v2,v3)),
                       fmaxf(fmaxf(v4,v5),fmaxf(v6,v7)));
      pm = fmaxf(pm, __shfl_xor(pm, 1));
      pm = fmaxf(pm, __shfl_xor(pm, 2));
      pm = fmaxf(pm, __shfl_xor(pm, 4));
      float mo = m_s[srow];
      float mn = (pm > mo + 11.54f) ? pm : mo;      // defer-max (log2 units)
      float p0 = __builtin_amdgcn_exp2f(v0-mn), p1 = __builtin_amdgcn_exp2f(v1-mn);
      float p2 = __builtin_amdgcn_exp2f(v2-mn), p3 = __builtin_amdgcn_exp2f(v3-mn);
      float p4 = __builtin_amdgcn_exp2f(v4-mn), p5 = __builtin_amdgcn_exp2f(v5-mn);
      float p6 = __builtin_amdgcn_exp2f(v6-mn), p7 = __builtin_amdgcn_exp2f(v7-mn);
      float sum = ((p0+p1)+(p2+p3)) + ((p4+p5)+(p6+p7));
      sum += __shfl_xor(sum, 1);
      sum += __shfl_xor(sum, 2);
      sum += __shfl_xor(sum, 4);
      if (sj == 0){
        float f = __builtin_amdgcn_exp2f(mo - mn);
        f_s[srow] = f;
        m_s[srow] = mn;
        l_s[srow] = l_s[srow]*f + sum;
      }
      uint32_t w0 = (uint32_t)f2h(p0) | ((uint32_t)f2h(p1)<<16);
      uint32_t w1 = (uint32_t)f2h(p2) | ((uint32_t)f2h(p3)<<16);
      uint32_t w2 = (uint32_t)f2h(p4) | ((uint32_t)f2h(p5)<<16);
      uint32_t w3 = (uint32_t)f2h(p6) | ((uint32_t)f2h(p7)<<16);
      uint4 pw = make_uint4(w0,w1,w2,w3);
      *(uint4*)((char*)Ps + srow*128 + ((sj ^ (srow&7))<<4)) = pw;
    }
    asm volatile("s_waitcnt lgkmcnt(0)" ::: "memory");
    __builtin_amdgcn_s_barrier();                   // B2: P + f_s published
    __builtin_amdgcn_sched_barrier(0);

    // ---- O rescale ----
    {
      float fx[2][4];
#pragma unroll
      for (int qt=0; qt<2; ++qt)
#pragma unroll
        for (int r=0; r<4; ++r)
          fx[qt][r] = f_s[qt*16 + fg*4 + r];
      bool nr = (fx[0][0]!=1.f)|(fx[0][1]!=1.f)|(fx[0][2]!=1.f)|(fx[0][3]!=1.f)|
                (fx[1][0]!=1.f)|(fx[1][1]!=1.f)|(fx[1][2]!=1.f)|(fx[1][3]!=1.f);
      if (__any(nr)){
#pragma unroll
        for (int qt=0; qt<2; ++qt)
#pragma unroll
          for (int dt=0; dt<8; ++dt)
#pragma unroll
            for (int r=0; r<4; ++r)
              acc[qt][dt][r] *= fx[qt][r];
      }
    }

    // ---- PV: 32q x 128d per wave; pa from Ps, bv = vreg ----
    __builtin_amdgcn_s_setprio(1);
#pragma unroll
    for (int vk=0; vk<2; ++vk){
      f16x8 pa[2];
#pragma unroll
      for (int qt=0; qt<2; ++qt){
        int q = qt*16 + fr;
        pa[qt] = *(const f16x8*)((const char*)Ps + q*128 + ((((vk<<2)|fg) ^ (q&7))<<4));
      }
#pragma unroll
      for (int qt=0; qt<2; ++qt)
#pragma unroll
        for (int dt=0; dt<8; ++dt)
          acc[qt][dt] = __builtin_amdgcn_mfma_f32_16x16x32_f16(pa[qt], vreg[vk][dt], acc[qt][dt], 0,0,0);
    }
    __builtin_amdgcn_s_setprio(0);
    // no barrier: B1(t+1) gates all Ps/f_s overwrites (proof in analysis)
  }

  // ---- epilogue: O /= l ----
  float linv[2][4];
#pragma unroll
  for (int qt=0; qt<2; ++qt)
#pragma unroll
    for (int r=0; r<4; ++r)
      linv[qt][r] = 1.0f / l_s[qt*16 + fg*4 + r];
  float* Ob = Out + ((size_t)batch*S_ + s0)*D_;
#pragma unroll
  for (int qt=0; qt<2; ++qt)
#pragma unroll
    for (int dt=0; dt<8; ++dt){
      int d = wd*128 + dt*16 + fr;
#pragma unroll
      for (int r=0; r<4; ++r){
        int q = qt*16 + fg*4 + r;
        Ob[(size_t)q*D_ + d] = acc[qt][dt][r] * linv[qt][r];
      }
    }
}

extern "C" void kernel_launch(void* const* d_in, const int* in_sizes, int n_in,
                              void* d_out, int out_size, void* d_ws, size_t ws_size,
                              hipStream_t stream)
{
  (void)in_sizes; (void)n_in; (void)out_size; (void)ws_size;
  const float* X  = (const float*)d_in[0];
  const float* Ww = (const float*)d_in[1];
  const float* Wb = (const float*)d_in[2];
  const float* Uw = (const float*)d_in[3];
  const float* Ub = (const float*)d_in[4];
  float* out = (float*)d_out;

  char* ws = (char*)d_ws;
  size_t off = 0;
  uint16_t* Xf = (uint16_t*)(ws + off); off += (size_t)M_TOTAL*D_*2;  // f16 [M][512]
  uint16_t* XT = (uint16_t*)(ws + off); off += (size_t)B_*D_*S_*2;    // f16 [B][512][2048]
  uint16_t* WT = (uint16_t*)(ws + off); off += (size_t)NPROJ*D_*2;    // f16 [1024][512]
  uint16_t* Qf = (uint16_t*)(ws + off); off += (size_t)M_TOTAL*U_*2;  // f16 [M][512]
  uint16_t* Kf = (uint16_t*)(ws + off); off += (size_t)M_TOTAL*U_*2;

  prep_w<<<dim3((NPROJ*D_)/256), 256, 0, stream>>>(Ww, Uw, WT);
  prep_x<<<dim3(S_/32, D_/32, B_), 256, 0, stream>>>(X, Xf, XT);

  gemm_proj<<<dim3(NPROJ/256, M_TOTAL/256, 1), 512, 0, stream>>>(
      Xf, D_, WT, D_, Qf, Kf, Wb, Ub, D_);

  flash_attn<<<dim3(B_ * (S_/QBLK)), 256, 0, stream>>>(Qf, Kf, XT, out);
}

// Round 10
// 212.518 us; speedup vs baseline: 1.3534x; 1.3534x over previous
//
#include <hip/hip_runtime.h>
#include <stdint.h>

#define B_ 8
#define S_ 2048
#define D_ 512
#define U_ 512
#define M_TOTAL (B_*S_)   // 16384
#define NPROJ (2*U_)      // 1024
#define QBLK 64
#define KVBLK 64
#define NIT (S_/KVBLK)    // 32
#define LOG2E 1.4426950408889634f

typedef __attribute__((ext_vector_type(8))) _Float16 f16x8;
typedef __attribute__((ext_vector_type(4))) float f32x4;
typedef __attribute__((ext_vector_type(16))) float f32x16;

__device__ __forceinline__ uint16_t f2h(float f){
  return __builtin_bit_cast(uint16_t, (_Float16)f);
}

__device__ __forceinline__ void gload16(const void* g, void* l){
  __builtin_amdgcn_global_load_lds(
      (const __attribute__((address_space(1))) void*)g,
      (__attribute__((address_space(3))) void*)l, 16, 0, 0);
}

// Stage one half-tile [ROWS x 64] f16 into linear LDS, global source pre-swizzled.
template<int ROWS>
__device__ __forceinline__ void stage_half(char* lbase, const uint16_t* __restrict__ gpanel,
                                           int ld, int wv, int lane){
  int r0 = wv*8 + (lane>>3);
  int gs = ((lane&7) ^ (r0&7)) << 3;
  gload16(gpanel + (size_t)r0*ld + gs, lbase + wv*1024);
  if constexpr (ROWS==128){
    gload16(gpanel + (size_t)(r0+64)*ld + gs, lbase + 8192 + wv*1024);
  }
}

// ---- prep: WT[u][d] = f16(W[d][u]); u<512 -> Ww, else Uw ----
__global__ __launch_bounds__(256) void prep_w(const float* __restrict__ Ww,
                                              const float* __restrict__ Uw,
                                              uint16_t* __restrict__ WT){
  int idx = blockIdx.x*256 + threadIdx.x;
  int u = idx >> 9;
  int d = idx & 511;
  float v = (u < U_) ? Ww[d*U_ + u] : Uw[d*U_ + (u-U_)];
  WT[idx] = f2h(v);
}

// ---- prep: Xf[b][s][d] f16 row-major; XT[b][d][s] f16 transposed ----
__global__ __launch_bounds__(256) void prep_x(const float* __restrict__ X,
                                              uint16_t* __restrict__ Xf,
                                              uint16_t* __restrict__ XT){
  __shared__ float tile[32][33];
  int b = blockIdx.z;
  int s0 = blockIdx.x * 32;
  int d0 = blockIdx.y * 32;
  int tid = threadIdx.x;
  int tr = tid >> 5;
  int tc = tid & 31;
  const float* Xb = X + (size_t)b*S_*D_;
#pragma unroll
  for (int i = 0; i < 32; i += 8){
    size_t off = (size_t)(s0+tr+i)*D_ + d0+tc;
    float v = Xb[off];
    tile[tr+i][tc] = v;
    Xf[(size_t)b*S_*D_ + off] = f2h(v);
  }
  __syncthreads();
  uint16_t* XTb = XT + (size_t)b*D_*S_;
#pragma unroll
  for (int i = 0; i < 32; i += 8)
    XTb[(size_t)(d0+tr+i)*S_ + s0+tc] = f2h(tile[tc][tr+i]);
}

// ---- 8-phase NT projection GEMM; Q output pre-scaled by log2(e) ----
__global__ __launch_bounds__(512, 2) void gemm_proj(
    const uint16_t* __restrict__ A, int lda,
    const uint16_t* __restrict__ Bp, int ldb,
    uint16_t* __restrict__ Qo, uint16_t* __restrict__ Ko,
    const float* __restrict__ biasW, const float* __restrict__ biasU,
    int KD)
{
  constexpr int AHALF = 128*128;
  constexpr int BHALF = 128*128;
  constexpr int DSTR  = 2*AHALF + 2*BHALF;
  __shared__ __align__(16) char smem[2*DSTR];

  const int m0 = blockIdx.y * 256;
  const int n0 = blockIdx.x * 256;
  const uint16_t* Apan = A  + (size_t)m0*lda;
  const uint16_t* Bpan = Bp + (size_t)n0*ldb;

  const int t512 = threadIdx.x;
  const int wv   = t512 >> 6;
  const int lane = t512 & 63;
  const int wm   = wv >> 2;
  const int wn   = wv & 3;
  const int fr   = lane & 15;
  const int fg   = lane >> 4;
  const int sw   = fr & 7;

  const int NT = KD >> 6;

  auto Aslot = [&](int par, int h){ return smem + par*DSTR + h*AHALF; };
  auto Bslot = [&](int par, int h){ return smem + par*DSTR + 2*AHALF + h*BHALF; };

  stage_half<128>(Aslot(0,0), Apan,                   lda, wv, lane);
  stage_half<128>(Aslot(0,1), Apan + (size_t)128*lda, lda, wv, lane);
  stage_half<128>(Bslot(0,0), Bpan,                   ldb, wv, lane);
  stage_half<128>(Bslot(0,1), Bpan + (size_t)128*ldb, ldb, wv, lane);
  if (NT > 1)
    stage_half<128>(Aslot(1,0), Apan + 64,            lda, wv, lane);
  asm volatile("s_waitcnt vmcnt(2)" ::: "memory");
  __builtin_amdgcn_s_barrier();

  f32x4 acc[8][4];
#pragma unroll
  for (int i=0;i<8;i++)
#pragma unroll
    for (int j=0;j<4;j++) acc[i][j] = (f32x4){0.f,0.f,0.f,0.f};

  for (int t = 0; t < NT; ++t){
    const int p = t & 1;
    const char* myA = Aslot(p, wm);
    const char* myB = Bslot(p, wn>>1);
    f16x8 af[8];

    auto rdA = [&](int ks){
#pragma unroll
      for (int mf=0; mf<8; ++mf)
        af[mf] = *(const f16x8*)(myA + (mf*16+fr)*128 + (((ks<<2)|fg) ^ sw)*16);
    };
    auto rdB = [&](int ks, int nh, f16x8& b0, f16x8& b1){
      int rb = (wn&1)*64 + nh*32 + fr;
      b0 = *(const f16x8*)(myB + rb*128      + (((ks<<2)|fg) ^ sw)*16);
      b1 = *(const f16x8*)(myB + (rb+16)*128 + (((ks<<2)|fg) ^ sw)*16);
    };
    auto mm = [&](int nh, f16x8 b0, f16x8 b1){
      __builtin_amdgcn_s_setprio(1);
#pragma unroll
      for (int mf=0; mf<8; ++mf){
        acc[mf][nh*2]   = __builtin_amdgcn_mfma_f32_16x16x32_f16(af[mf], b0, acc[mf][nh*2],   0,0,0);
        acc[mf][nh*2+1] = __builtin_amdgcn_mfma_f32_16x16x32_f16(af[mf], b1, acc[mf][nh*2+1], 0,0,0);
      }
      __builtin_amdgcn_s_setprio(0);
    };

    f16x8 b0, b1;
    rdA(0); rdB(0, 0, b0, b1);
    if (t+1 < NT)
      stage_half<128>(Aslot(p^1,1), Apan + (size_t)128*lda + (t+1)*64, lda, wv, lane);
    __builtin_amdgcn_s_barrier();
    mm(0, b0, b1);
    __builtin_amdgcn_s_barrier();
    rdB(0, 1, b0, b1);
    if (t+1 < NT)
      stage_half<128>(Bslot(p^1,0), Bpan + (t+1)*64, ldb, wv, lane);
    __builtin_amdgcn_s_barrier();
    mm(1, b0, b1);
    __builtin_amdgcn_s_barrier();
    rdA(1); rdB(1, 0, b0, b1);
    if (t+1 < NT)
      stage_half<128>(Bslot(p^1,1), Bpan + (size_t)128*ldb + (t+1)*64, ldb, wv, lane);
    __builtin_amdgcn_s_barrier();
    mm(0, b0, b1);
    __builtin_amdgcn_s_barrier();
    rdB(1, 1, b0, b1);
    if (t+2 < NT)
      stage_half<128>(Aslot(p,0), Apan + (t+2)*64, lda, wv, lane);
    __builtin_amdgcn_s_barrier();
    mm(1, b0, b1);
    asm volatile("s_waitcnt vmcnt(2)" ::: "memory");
    __builtin_amdgcn_s_barrier();
  }

#pragma unroll
  for (int mf=0; mf<8; ++mf)
#pragma unroll
    for (int nf=0; nf<4; ++nf){
      int col  = n0 + wn*64 + nf*16 + fr;
      int rowb = m0 + wm*128 + mf*16 + fg*4;
      f32x4 a = acc[mf][nf];
      float bias = (col < U_) ? biasW[col] : biasU[col - U_];
      if (col < U_){
#pragma unroll
        for (int r=0;r<4;r++) Qo[(size_t)(rowb+r)*U_ + col] = f2h((a[r] + bias)*LOG2E);
      } else {
#pragma unroll
        for (int r=0;r<4;r++) Ko[(size_t)(rowb+r)*U_ + col - U_] = f2h(a[r] + bias);
      }
    }
}

// ---- wave-specialized fused flash attention v2 ----
// 8 waves: wv<4 QK (mt kv-half, nt q-half; 32kv x 32q, full d via LDS Q+K),
// wv>=4 PV (dh d-quarter; 64q x 128d, V direct global, P one iter behind).
// Q in LDS (64KB, staged once). K single-buffered LDS (64KB): restaged at
// post-A top (all tile-t reads done at barrier A), certified vmcnt(0)->B.
// Ps single-buffered (PV pre-A read / QK post-A write split by barrier A).
__global__ __launch_bounds__(512, 2) void flash_ws(
    const uint16_t* __restrict__ Qf,   // [B*S][512] f16 (pre-scaled by log2e)
    const uint16_t* __restrict__ Kf,   // [B*S][512] f16
    const uint16_t* __restrict__ XT,   // [B][512][2048] f16
    float* __restrict__ Out)           // [B*S][512] f32
{
  __shared__ __align__(16) uint16_t Qs[QBLK][512];    // 64 KB, swz g^=(row&31)
  __shared__ __align__(16) uint16_t Ks[KVBLK][512];   // 64 KB, swz g^=(row&31)
  __shared__ __align__(16) uint16_t Ps[QBLK][KVBLK];  // 8 KB,  swz g^=(q&7)
  __shared__ float pm_s[2][QBLK];                     // [mt][q] partial max
  __shared__ float ps_s[2][2][QBLK];                  // [buf][mt][q] partial sums
  __shared__ float f_s[2][QBLK];                      // [buf][q] rescale factor
  __shared__ float l_s[QBLK];
  __shared__ unsigned flag_s[2][2];                   // [buf][nt]

  const int bid   = blockIdx.x;
  const int batch = bid & 7;
  const int s0    = (bid >> 3) * QBLK;

  const int t512 = threadIdx.x;
  const int wv   = t512 >> 6;
  const int lane = t512 & 63;
  const int l31  = lane & 31;
  const int l5   = lane >> 5;
  const bool isQK = (wv < 4);
  const int mt = (wv >> 1) & 1;
  const int nt = wv & 1;
  const int dh = wv & 3;       // PV d-quarter

  const uint16_t* Krow = Kf + (size_t)batch*S_*U_;
  const uint16_t* Vt   = XT + (size_t)batch*D_*S_;

  // ---- PV accumulators ----
  f32x16 acc[2][4];
#pragma unroll
  for (int mf=0; mf<2; ++mf)
#pragma unroll
    for (int nf=0; nf<4; ++nf)
#pragma unroll
      for (int r=0; r<16; ++r) acc[mf][nf][r] = 0.f;

  float m_reg = -3.0e38f, l_reg = 0.f, f_reg = 1.f;

  // ---- prologue: stage Qs and Ks(0), all 512 threads, swizzled source ----
  {
    const uint16_t* Qb = Qf + ((size_t)batch*S_ + s0)*U_;
#pragma unroll
    for (int i=0; i<8; ++i){
      int c = i*512 + t512;
      int r = c >> 6, gl = c & 63;
      int gs = gl ^ (r & 31);
      gload16(Qb + (size_t)r*U_ + gs*8, (char*)Qs + (i*512 + wv*64)*16);
    }
#pragma unroll
    for (int i=0; i<8; ++i){
      int c = i*512 + t512;
      int r = c >> 6, gl = c & 63;
      int gs = gl ^ (r & 31);
      gload16(Krow + (size_t)r*U_ + gs*8, (char*)Ks + (i*512 + wv*64)*16);
    }
  }
  asm volatile("s_waitcnt vmcnt(0) lgkmcnt(0)" ::: "memory");
  __builtin_amdgcn_s_barrier();                       // Qs + K(0) certified
  __builtin_amdgcn_sched_barrier(0);

  for (int t = 0; t <= NIT; ++t){
    const int buf = t & 1, pbuf = buf ^ 1;
    float sv[16];

    // ---- l-update: runs for ALL t>=1 including t==NIT (R9 bug fix) ----
    if (isQK && t >= 1){
      int q = nt*32 + l31;
      float s01 = ps_s[pbuf][0][q] + ps_s[pbuf][1][q];
      l_reg = l_reg * f_reg + s01;
    }

    // ================= pre-A segment =================
    if (isQK && t < NIT){
      // QK^T: A = K rows mt*32+l31, B = Q rows nt*32+l31; both LDS, same swz
      f32x16 sA, sB;
#pragma unroll
      for (int r=0;r<16;++r){ sA[r]=0.f; sB[r]=0.f; }
      const char* Kb = (const char*)Ks + (mt*32 + l31)*1024;
      const char* Qb = (const char*)Qs + (nt*32 + l31)*1024;
      __builtin_amdgcn_s_setprio(1);
#pragma unroll
      for (int kk=0; kk<32; kk+=2){
        int g0 = (( kk   <<1)|l5) ^ l31;
        int g1 = (((kk+1)<<1)|l5) ^ l31;
        f16x8 k0 = *(const f16x8*)(Kb + g0*16);
        f16x8 q0 = *(const f16x8*)(Qb + g0*16);
        f16x8 k1 = *(const f16x8*)(Kb + g1*16);
        f16x8 q1 = *(const f16x8*)(Qb + g1*16);
        sA = __builtin_amdgcn_mfma_f32_32x32x16_f16(k0, q0, sA, 0,0,0);
        sB = __builtin_amdgcn_mfma_f32_32x32x16_f16(k1, q1, sB, 0,0,0);
      }
      __builtin_amdgcn_s_setprio(0);
#pragma unroll
      for (int r=0;r<16;++r) sv[r] = sA[r] + sB[r];
      float pmax = sv[0];
#pragma unroll
      for (int r=1;r<16;++r) pmax = fmaxf(pmax, sv[r]);
      pmax = fmaxf(pmax, __shfl_xor(pmax, 32));
      if (lane < 32) pm_s[mt][nt*32 + l31] = pmax;
      asm volatile("s_waitcnt lgkmcnt(0)" ::: "memory");
    }
    if (!isQK && t >= 1){
      const int it = t - 1;
      // rescale on flag (from QK post-A of t-1, certified at barrier B)
      unsigned flg = flag_s[pbuf][0] | flag_s[pbuf][1];
      if (flg){
#pragma unroll
        for (int mf=0; mf<2; ++mf)
#pragma unroll
          for (int rq=0; rq<4; ++rq){
            int q0 = mf*32 + 8*rq + 4*l5;
            float4 fx = *(const float4*)&f_s[pbuf][q0];
#pragma unroll
            for (int nf=0; nf<4; ++nf){
              acc[mf][nf][rq*4+0] *= fx.x;
              acc[mf][nf][rq*4+1] *= fx.y;
              acc[mf][nf][rq*4+2] *= fx.z;
              acc[mf][nf][rq*4+3] *= fx.w;
            }
          }
      }
      // PV: per-kk V loads (reduce reg pressure) + P from Ps
      __builtin_amdgcn_s_setprio(1);
#pragma unroll
      for (int kk=0; kk<4; ++kk){
        f16x8 vb[4];
#pragma unroll
        for (int nf=0; nf<4; ++nf){
          int d = dh*128 + nf*32 + l31;
          vb[nf] = *(const f16x8*)(Vt + (size_t)d*S_ + it*KVBLK + kk*16 + 8*l5);
        }
        f16x8 pa[2];
#pragma unroll
        for (int mf=0; mf<2; ++mf){
          int q = mf*32 + l31;
          pa[mf] = *(const f16x8*)((const char*)Ps + q*128
                                   + ((((kk<<1)|l5) ^ (q&7))<<4));
        }
#pragma unroll
        for (int nf=0; nf<4; ++nf){
          acc[0][nf] = __builtin_amdgcn_mfma_f32_32x32x16_f16(pa[0], vb[nf], acc[0][nf], 0,0,0);
          acc[1][nf] = __builtin_amdgcn_mfma_f32_32x32x16_f16(pa[1], vb[nf], acc[1][nf], 0,0,0);
        }
      }
      __builtin_amdgcn_s_setprio(0);
    }
    __builtin_amdgcn_s_barrier();                     // A: pm published, Ks reads done
    __builtin_amdgcn_sched_barrier(0);

    // ================= post-A segment =================
    if (isQK && t < NIT){
      // restage K(t+1) over Ks (single buffer, safe: all reads done at A)
      if (t+1 < NIT){
        int tq = wv*64 + lane;
#pragma unroll
        for (int i=0; i<16; ++i){
          int c = i*256 + tq;
          int r = c >> 6, gl = c & 63;
          int gs = gl ^ (r & 31);
          gload16(Krow + (size_t)((t+1)*KVBLK + r)*U_ + gs*8,
                  (char*)Ks + (i*256 + wv*64)*16);
        }
      }
      const int q = nt*32 + l31;
      float pm = fmaxf(pm_s[0][q], pm_s[1][q]);
      bool chg = pm > m_reg + 11.54f;                 // defer-max (log2 units)
      unsigned anychg = __any(chg) ? 1u : 0u;
      float mn = chg ? pm : m_reg;
      f_reg = __builtin_amdgcn_exp2f(m_reg - mn);
      m_reg = mn;
      float p[16];
      float psum = 0.f;
#pragma unroll
      for (int r=0;r<16;++r){ p[r] = __builtin_amdgcn_exp2f(sv[r] - mn); psum += p[r]; }
      psum += __shfl_xor(psum, 32);
      // write P at true kv addresses (C/D row formula), swizzled by q&7
#pragma unroll
      for (int q4=0; q4<4; ++q4)
#pragma unroll
        for (int pp=0; pp<2; ++pp){
          uint32_t w = (uint32_t)f2h(p[q4*4+2*pp]) | ((uint32_t)f2h(p[q4*4+2*pp+1])<<16);
          int g = (mt*4 + q4) ^ (q & 7);
          *(uint32_t*)((char*)Ps + q*128 + g*16 + 8*l5 + 4*pp) = w;
        }
      if (lane < 32){
        ps_s[buf][mt][q] = psum;
        if (mt == 0) f_s[buf][q] = f_reg;
      }
      if (mt == 0 && lane == 0) flag_s[buf][nt] = anychg;
      asm volatile("s_waitcnt lgkmcnt(0)" ::: "memory");
      asm volatile("s_waitcnt vmcnt(0)" ::: "memory");  // K(t+1) landed
    }
    __builtin_amdgcn_s_barrier();                     // B: P/f/sums + K(t+1) certified
    __builtin_amdgcn_sched_barrier(0);
  }

  // ---- epilogue: QK publishes final l; PV normalizes and stores ----
  if (isQK && mt == 0 && lane < 32) l_s[nt*32 + l31] = l_reg;
  asm volatile("s_waitcnt lgkmcnt(0)" ::: "memory");
  __builtin_amdgcn_s_barrier();

  if (!isQK){
    float* Ob = Out + ((size_t)batch*S_ + s0)*D_;
#pragma unroll
    for (int mf=0; mf<2; ++mf)
#pragma unroll
      for (int rq=0; rq<4; ++rq){
        int q0 = mf*32 + 8*rq + 4*l5;
        float4 lv = *(const float4*)&l_s[q0];
        float4 li = make_float4(1.f/lv.x, 1.f/lv.y, 1.f/lv.z, 1.f/lv.w);
#pragma unroll
        for (int nf=0; nf<4; ++nf){
          int d = dh*128 + nf*32 + l31;
          Ob[(size_t)(q0+0)*D_ + d] = acc[mf][nf][rq*4+0] * li.x;
          Ob[(size_t)(q0+1)*D_ + d] = acc[mf][nf][rq*4+1] * li.y;
          Ob[(size_t)(q0+2)*D_ + d] = acc[mf][nf][rq*4+2] * li.z;
          Ob[(size_t)(q0+3)*D_ + d] = acc[mf][nf][rq*4+3] * li.w;
        }
      }
  }
}

extern "C" void kernel_launch(void* const* d_in, const int* in_sizes, int n_in,
                              void* d_out, int out_size, void* d_ws, size_t ws_size,
                              hipStream_t stream)
{
  (void)in_sizes; (void)n_in; (void)out_size; (void)ws_size;
  const float* X  = (const float*)d_in[0];
  const float* Ww = (const float*)d_in[1];
  const float* Wb = (const float*)d_in[2];
  const float* Uw = (const float*)d_in[3];
  const float* Ub = (const float*)d_in[4];
  float* out = (float*)d_out;

  char* ws = (char*)d_ws;
  size_t off = 0;
  uint16_t* Xf = (uint16_t*)(ws + off); off += (size_t)M_TOTAL*D_*2;  // f16 [M][512]
  uint16_t* XT = (uint16_t*)(ws + off); off += (size_t)B_*D_*S_*2;    // f16 [B][512][2048]
  uint16_t* WT = (uint16_t*)(ws + off); off += (size_t)NPROJ*D_*2;    // f16 [1024][512]
  uint16_t* Qf = (uint16_t*)(ws + off); off += (size_t)M_TOTAL*U_*2;  // f16 [M][512]
  uint16_t* Kf = (uint16_t*)(ws + off); off += (size_t)M_TOTAL*U_*2;

  prep_w<<<dim3((NPROJ*D_)/256), 256, 0, stream>>>(Ww, Uw, WT);
  prep_x<<<dim3(S_/32, D_/32, B_), 256, 0, stream>>>(X, Xf, XT);

  gemm_proj<<<dim3(NPROJ/256, M_TOTAL/256, 1), 512, 0, stream>>>(
      Xf, D_, WT, D_, Qf, Kf, Wb, Ub, D_);

  flash_ws<<<dim3(B_ * (S_/QBLK)), 512, 0, stream>>>(Qf, Kf, XT, out);
}